// Round 14
// baseline (98.400 us; speedup 1.0000x reference)
//
#include <hip/hip_runtime.h>

#define N_NODES 50000
#define N_EDGES 1250000
#define DIM 64
#define NUM_CLASS 10
#define NUM_GRAPHS 256
#define CAP 64        // padded CSR row capacity (deg mean 25, sd 5; max deg << 64)
#define BSHIFT 6      // 64 nodes per bucket
#define NB ((N_NODES + 63) / 64)          // 782 buckets
#define BCAP 2048     // entries per bucket (mean ~1600, sd ~40; +11 sigma)
#define I4_TOTAL (N_EDGES / 4)            // 312500, exact
#define I4_PER_BLOCK 2048                 // 8192 edges/block -> 153 blocks (~60% CU fill)

typedef __attribute__((ext_vector_type(8))) short short8v;   // 8 bf16 = 4 VGPR
typedef __attribute__((ext_vector_type(4))) float float4v;   // MFMA C/D
typedef __attribute__((ext_vector_type(2))) float float2v;

#if defined(__has_builtin)
#if __has_builtin(__builtin_amdgcn_cvt_pk_f32_fp8) && __has_builtin(__builtin_amdgcn_cvt_pk_fp8_f32)
#define HW_FP8 1
#endif
#endif

__device__ inline unsigned short f2bf_rne(float f) {
    unsigned b = __float_as_uint(f);
    return (unsigned short)((b + 0x7fff + ((b >> 16) & 1)) >> 16);
}
__device__ inline float bf2f(unsigned short u) {
    return __uint_as_float((unsigned)u << 16);
}

// ---- fp8 e4m3fn software helpers (fallback) -------------------------------
__device__ inline unsigned f2e4m3_sw(float x) {
    float af = fabsf(x);
    unsigned s = (__float_as_uint(x) >> 31) << 7;
    if (af >= 448.f) return s | 0x7E;
    if (af < 0.015625f) {
        int n = (int)rintf(af * 512.f);
        if (n >= 8) return s | 0x08;
        return s | (unsigned)n;
    }
    unsigned u = __float_as_uint(af);
    u += 0x7FFFF + ((u >> 20) & 1);
    int e32 = (int)(u >> 23) - 127;
    if (e32 > 8) return s | 0x7E;
    unsigned m = (u >> 20) & 7;
    return s | ((unsigned)(e32 + 7) << 3) | m;
}
__device__ inline float e4m3f_sw(unsigned b) {
    unsigned e = (b >> 3) & 15;
    unsigned nz = e ? 1u : 0u;
    float mant = (float)((b & 7) + (nz << 3));
    float v = ldexpf(mant, (int)e - 9 - (int)nz);
    return (b & 0x80) ? -v : v;
}

__device__ inline float4 dec4(unsigned q) {
#ifdef HW_FP8
    float2v lo = __builtin_amdgcn_cvt_pk_f32_fp8(q, false);
    float2v hi = __builtin_amdgcn_cvt_pk_f32_fp8(q, true);
    return make_float4(lo.x, lo.y, hi.x, hi.y);
#else
    return make_float4(e4m3f_sw(q & 0xff), e4m3f_sw((q >> 8) & 0xff),
                       e4m3f_sw((q >> 16) & 0xff), e4m3f_sw(q >> 24));
#endif
}
__device__ inline unsigned enc4(float a, float b, float c, float d) {
#ifdef HW_FP8
    int u = __builtin_amdgcn_cvt_pk_fp8_f32(a, b, 0, false);
    u = __builtin_amdgcn_cvt_pk_fp8_f32(c, d, u, true);
    return (unsigned)u;
#else
    return f2e4m3_sw(a) | (f2e4m3_sw(b) << 8) | (f2e4m3_sw(c) << 16) | (f2e4m3_sw(d) << 24);
#endif
}
__device__ inline unsigned char enc1(float a) {
#ifdef HW_FP8
    return (unsigned char)(__builtin_amdgcn_cvt_pk_fp8_f32(a, a, 0, false) & 0xff);
#else
    return (unsigned char)f2e4m3_sw(a);
#endif
}

// ---------------------------------------------------------------------------
// Phase A: bucket edges by dst>>6 (LDS histogram -> chunked dense writes).
// ---------------------------------------------------------------------------
__global__ __launch_bounds__(512) void bucket_kernel(
    const int4* __restrict__ src4, const int4* __restrict__ dst4,
    int* __restrict__ bcount, unsigned int* __restrict__ bdata)
{
    __shared__ int hist[NB];
    __shared__ int base[NB];
    const int tid = threadIdx.x;
    for (int k = tid; k < NB; k += 512) hist[k] = 0;
    __syncthreads();

    const int i4base = blockIdx.x * I4_PER_BLOCK;
    const int i4end = min(i4base + I4_PER_BLOCK, I4_TOTAL);

    for (int idx = i4base + tid; idx < i4end; idx += 512) {
        int4 d = dst4[idx];
        atomicAdd(&hist[d.x >> BSHIFT], 1);
        atomicAdd(&hist[d.y >> BSHIFT], 1);
        atomicAdd(&hist[d.z >> BSHIFT], 1);
        atomicAdd(&hist[d.w >> BSHIFT], 1);
    }
    __syncthreads();

    for (int k = tid; k < NB; k += 512) {
        int c = hist[k];
        base[k] = c ? atomicAdd(&bcount[k], c) : 0;
        hist[k] = 0;   // reuse as local cursor
    }
    __syncthreads();

    for (int idx = i4base + tid; idx < i4end; idx += 512) {
        int4 s = src4[idx];   // L2-hit re-read
        int4 d = dst4[idx];
        int k, p;
        k = d.x >> BSHIFT; p = base[k] + atomicAdd(&hist[k], 1);
        if (p < BCAP) bdata[(size_t)k * BCAP + p] = ((unsigned)(d.x & 63) << 16) | (unsigned)s.x;
        k = d.y >> BSHIFT; p = base[k] + atomicAdd(&hist[k], 1);
        if (p < BCAP) bdata[(size_t)k * BCAP + p] = ((unsigned)(d.y & 63) << 16) | (unsigned)s.y;
        k = d.z >> BSHIFT; p = base[k] + atomicAdd(&hist[k], 1);
        if (p < BCAP) bdata[(size_t)k * BCAP + p] = ((unsigned)(d.z & 63) << 16) | (unsigned)s.z;
        k = d.w >> BSHIFT; p = base[k] + atomicAdd(&hist[k], 1);
        if (p < BCAP) bdata[(size_t)k * BCAP + p] = ((unsigned)(d.w & 63) << 16) | (unsigned)s.w;
    }
}

// ---------------------------------------------------------------------------
// Phase B: one block per bucket. Build 64 padded CSR rows in LDS, stream out.
// ---------------------------------------------------------------------------
__global__ __launch_bounds__(256) void csr_build_kernel(
    const int* __restrict__ bcount, const unsigned int* __restrict__ bdata,
    int* __restrict__ deg, unsigned short* __restrict__ csr)
{
    __shared__ unsigned short lcsr[64 * CAP];   // 8 KB
    __shared__ int ldeg[64];
    const int tid = threadIdx.x;
    const int bk = blockIdx.x;
    if (tid < 64) ldeg[tid] = 0;
    __syncthreads();

    const int cnt = min(bcount[bk], BCAP);
    for (int i = tid; i < cnt; i += 256) {
        unsigned int e = bdata[(size_t)bk * BCAP + i];
        int d = (int)(e >> 16);
        int p = atomicAdd(&ldeg[d], 1);
        if (p < CAP) lcsr[d * CAP + p] = (unsigned short)(e & 0xffff);
    }
    __syncthreads();

    const int node0 = bk << BSHIFT;
    const int nlocal = min(64, N_NODES - node0);
    uint4* csr16 = (uint4*)(csr + (size_t)node0 * CAP);
    const uint4* l16 = (const uint4*)lcsr;
    for (int i = tid; i < nlocal * 8; i += 256) csr16[i] = l16[i];
    if (tid < nlocal) deg[node0 + tid] = ldeg[tid];
}

// ---------------------------------------------------------------------------
// prep: [0,3125) x0->fp8; [3125,3253) pack W; block 3253 zero bcount + G.
// ---------------------------------------------------------------------------
__global__ __launch_bounds__(256) void prep_kernel(
    const float4* __restrict__ x04, const float* __restrict__ W1,
    const float* __restrict__ W2, unsigned* __restrict__ x0q,
    unsigned short* __restrict__ WB, int* __restrict__ bcount,
    float* __restrict__ G)
{
    const int bid = blockIdx.x;
    const int tid = threadIdx.x;
    if (bid < 3125) {
        int t = bid * 256 + tid;            // < 800000
        float4 v = x04[t];
        x0q[t] = enc4(v.x, v.y, v.z, v.w);
    } else if (bid < 3253) {
        int t = (bid - 3125) * 256 + tid;   // 0..32767
        int layer = t >> 14;
        int r = t & 16383;
        int i    = r & 7;
        int lane = (r >> 3) & 63;
        int h    = (r >> 9) & 1;
        int ct   = (r >> 10) & 3;
        int kt   = (r >> 12) & 3;
        int k   = kt * 32 + (lane >> 4) * 8 + i;
        int col = ct * 16 + (lane & 15);
        const float* W = layer ? W2 : W1;
        float x = W[k * 64 + col];
        unsigned bits = __float_as_uint(x);
        unsigned short u;
        if (h == 0) {
            u = (unsigned short)(bits >> 16);
        } else {
            float y = x - __uint_as_float(bits & 0xffff0000u);
            u = (unsigned short)(__float_as_uint(y) >> 16);
        }
        WB[t] = u;
    } else {
        for (int k = tid; k < NB; k += 256) bcount[k] = 0;
        for (int k = tid; k < NUM_GRAPHS * DIM; k += 256) G[k] = 0.f;
    }
}

// gather-accumulate 8 neighbors' fp8 quads into agg
#define GATHER8(row, j, agg)                                                  \
    {                                                                         \
        ushort4 sa = *(const ushort4*)((row) + (j));                          \
        ushort4 sb = *(const ushort4*)((row) + (j) + 4);                      \
        unsigned q0 = xq[(size_t)sa.x * 16 + c];                              \
        unsigned q1 = xq[(size_t)sa.y * 16 + c];                              \
        unsigned q2 = xq[(size_t)sa.z * 16 + c];                              \
        unsigned q3 = xq[(size_t)sa.w * 16 + c];                              \
        unsigned q4 = xq[(size_t)sb.x * 16 + c];                              \
        unsigned q5 = xq[(size_t)sb.y * 16 + c];                              \
        unsigned q6 = xq[(size_t)sb.z * 16 + c];                              \
        unsigned q7 = xq[(size_t)sb.w * 16 + c];                              \
        float4 f0 = dec4(q0), f1 = dec4(q1), f2 = dec4(q2), f3 = dec4(q3);    \
        float4 f4 = dec4(q4), f5 = dec4(q5), f6 = dec4(q6), f7 = dec4(q7);    \
        agg.x += (f0.x + f1.x) + (f2.x + f3.x) + (f4.x + f5.x) + (f6.x + f7.x); \
        agg.y += (f0.y + f1.y) + (f2.y + f3.y) + (f4.y + f5.y) + (f6.y + f7.y); \
        agg.z += (f0.z + f1.z) + (f2.z + f3.z) + (f4.z + f5.z) + (f6.z + f7.z); \
        agg.w += (f0.w + f1.w) + (f2.w + f3.w) + (f4.w + f5.w) + (f6.w + f7.w); \
    }

// ---------------------------------------------------------------------------
// Fused SAGE layer. Gather from fp8 copy (64 B/row, L2-resident), HW cvt
// decode. The group's TWO nodes are gathered INTERLEAVED (16 independent
// line-fetches in flight over the common degree prefix) to hide L1-miss
// latency. f32 accumulate into hT[128][33]; self from f32 (L1) or bf16 (L2).
// MFMA GEMM (16x16x32 bf16, 3-term hi/lo). Epilogue: L1 -> bf16+fp8 stores;
// L2 -> fused per-graph segmented sum-pool (batch sorted) into G.
// D layout (m89-verified): col=lane&15, row=(lane>>4)*4+reg.
// ---------------------------------------------------------------------------
__global__ __launch_bounds__(256) void sage_layer_kernel(
    const float4* __restrict__ xs4,          // f32 self or null
    const ushort4* __restrict__ xsb,         // bf16 self or null
    const unsigned* __restrict__ xq,         // fp8 gather features [N][16]
    const int* __restrict__ deg,
    const unsigned short* __restrict__ csr,
    const unsigned short* __restrict__ WB,   // packed B-frags (this layer)
    const float* __restrict__ b,             // [64]
    unsigned short* __restrict__ outb,       // bf16 out or null
    unsigned char* __restrict__ outq,        // fp8 out or null
    float* __restrict__ G,                   // pooled sums or null
    const int* __restrict__ batch)
{
    __shared__ float hT[128][33];            // phase2 aliases as out[32][66]
    __shared__ int batch_lds[32];

    const int tid = threadIdx.x;
    const int g = tid >> 4;     // gather group 0..15
    const int c = tid & 15;     // column quad 0..15 (elements 4c..4c+3)
    const int n0 = blockIdx.x * 32;

    // ---- Phase 1: dual-node interleaved gather-aggregate ----
    const int nlA = g, nlB = g + 16;
    const int nA = n0 + nlA, nB = n0 + nlB;
    const bool vA = (nA < N_NODES), vB = (nB < N_NODES);

    float4 xvA = make_float4(0.f, 0.f, 0.f, 0.f), xvB = xvA;
    float4 agA = xvA, agB = xvA;
    int dA = 0, dB = 0;
    const unsigned short* rowA = csr;
    const unsigned short* rowB = csr;
    if (vA) {
        if (xs4) xvA = xs4[(size_t)nA * 16 + c];
        else { ushort4 u = xsb[(size_t)nA * 16 + c];
               xvA = make_float4(bf2f(u.x), bf2f(u.y), bf2f(u.z), bf2f(u.w)); }
        dA = min(deg[nA], CAP);
        rowA = csr + (size_t)nA * CAP;
    }
    if (vB) {
        if (xs4) xvB = xs4[(size_t)nB * 16 + c];
        else { ushort4 u = xsb[(size_t)nB * 16 + c];
               xvB = make_float4(bf2f(u.x), bf2f(u.y), bf2f(u.z), bf2f(u.w)); }
        dB = min(deg[nB], CAP);
        rowB = csr + (size_t)nB * CAP;
    }

    // interleaved common prefix: 16 gathers in flight
    int j = 0;
    const int dmin8 = (dA < dB ? dA : dB) & ~7;
    for (; j < dmin8; j += 8) {
        ushort4 ia0 = *(const ushort4*)(rowA + j);
        ushort4 ia1 = *(const ushort4*)(rowA + j + 4);
        ushort4 ib0 = *(const ushort4*)(rowB + j);
        ushort4 ib1 = *(const ushort4*)(rowB + j + 4);
        unsigned a0 = xq[(size_t)ia0.x * 16 + c];
        unsigned a1 = xq[(size_t)ia0.y * 16 + c];
        unsigned a2 = xq[(size_t)ia0.z * 16 + c];
        unsigned a3 = xq[(size_t)ia0.w * 16 + c];
        unsigned a4 = xq[(size_t)ia1.x * 16 + c];
        unsigned a5 = xq[(size_t)ia1.y * 16 + c];
        unsigned a6 = xq[(size_t)ia1.z * 16 + c];
        unsigned a7 = xq[(size_t)ia1.w * 16 + c];
        unsigned b0 = xq[(size_t)ib0.x * 16 + c];
        unsigned b1 = xq[(size_t)ib0.y * 16 + c];
        unsigned b2 = xq[(size_t)ib0.z * 16 + c];
        unsigned b3 = xq[(size_t)ib0.w * 16 + c];
        unsigned b4 = xq[(size_t)ib1.x * 16 + c];
        unsigned b5 = xq[(size_t)ib1.y * 16 + c];
        unsigned b6 = xq[(size_t)ib1.z * 16 + c];
        unsigned b7 = xq[(size_t)ib1.w * 16 + c];
        float4 f0 = dec4(a0), f1 = dec4(a1), f2 = dec4(a2), f3 = dec4(a3);
        float4 f4 = dec4(a4), f5 = dec4(a5), f6 = dec4(a6), f7 = dec4(a7);
        agA.x += (f0.x + f1.x) + (f2.x + f3.x) + (f4.x + f5.x) + (f6.x + f7.x);
        agA.y += (f0.y + f1.y) + (f2.y + f3.y) + (f4.y + f5.y) + (f6.y + f7.y);
        agA.z += (f0.z + f1.z) + (f2.z + f3.z) + (f4.z + f5.z) + (f6.z + f7.z);
        agA.w += (f0.w + f1.w) + (f2.w + f3.w) + (f4.w + f5.w) + (f6.w + f7.w);
        f0 = dec4(b0); f1 = dec4(b1); f2 = dec4(b2); f3 = dec4(b3);
        f4 = dec4(b4); f5 = dec4(b5); f6 = dec4(b6); f7 = dec4(b7);
        agB.x += (f0.x + f1.x) + (f2.x + f3.x) + (f4.x + f5.x) + (f6.x + f7.x);
        agB.y += (f0.y + f1.y) + (f2.y + f3.y) + (f4.y + f5.y) + (f6.y + f7.y);
        agB.z += (f0.z + f1.z) + (f2.z + f3.z) + (f4.z + f5.z) + (f6.z + f7.z);
        agB.w += (f0.w + f1.w) + (f2.w + f3.w) + (f4.w + f5.w) + (f6.w + f7.w);
    }
    // tails
    int ja = j, jb = j;
    for (; ja + 8 <= dA; ja += 8) GATHER8(rowA, ja, agA);
    for (; ja < dA; ++ja) {
        float4 f = dec4(xq[(size_t)rowA[ja] * 16 + c]);
        agA.x += f.x; agA.y += f.y; agA.z += f.z; agA.w += f.w;
    }
    for (; jb + 8 <= dB; jb += 8) GATHER8(rowB, jb, agB);
    for (; jb < dB; ++jb) {
        float4 f = dec4(xq[(size_t)rowB[jb] * 16 + c]);
        agB.x += f.x; agB.y += f.y; agB.z += f.z; agB.w += f.w;
    }

    hT[4 * c + 0][nlA] = xvA.x;
    hT[4 * c + 1][nlA] = xvA.y;
    hT[4 * c + 2][nlA] = xvA.z;
    hT[4 * c + 3][nlA] = xvA.w;
    hT[64 + 4 * c + 0][nlA] = agA.x;
    hT[64 + 4 * c + 1][nlA] = agA.y;
    hT[64 + 4 * c + 2][nlA] = agA.z;
    hT[64 + 4 * c + 3][nlA] = agA.w;
    hT[4 * c + 0][nlB] = xvB.x;
    hT[4 * c + 1][nlB] = xvB.y;
    hT[4 * c + 2][nlB] = xvB.z;
    hT[4 * c + 3][nlB] = xvB.w;
    hT[64 + 4 * c + 0][nlB] = agB.x;
    hT[64 + 4 * c + 1][nlB] = agB.y;
    hT[64 + 4 * c + 2][nlB] = agB.z;
    hT[64 + 4 * c + 3][nlB] = agB.w;
    __syncthreads();

    // ---- Phase 2: MFMA GEMM ----
    const int lane = tid & 63;
    const int wid  = tid >> 6;      // 0..3
    const int rt   = wid >> 1;      // row-tile 0..1
    const int ct0  = (wid & 1) * 2; // col-tiles ct0, ct0+1
    const int r  = lane & 15;
    const int q  = lane >> 4;

    const int col0 = (ct0 + 0) * 16 + r;
    const int col1 = (ct0 + 1) * 16 + r;
    const float bv0 = b[col0];
    const float bv1 = b[col1];
    float4v acc0 = {bv0, bv0, bv0, bv0};
    float4v acc1 = {bv1, bv1, bv1, bv1};

    #pragma unroll
    for (int kt = 0; kt < 4; ++kt) {
        short8v a_hi, a_lo;
        #pragma unroll
        for (int i = 0; i < 8; ++i) {
            float av = hT[kt * 32 + q * 8 + i][rt * 16 + r];
            unsigned bits = __float_as_uint(av);
            a_hi[i] = (short)(bits >> 16);
            float y = av - __uint_as_float(bits & 0xffff0000u);
            a_lo[i] = (short)(__float_as_uint(y) >> 16);
        }
        const unsigned short* Wk = WB + kt * 4096;
        const short8v bh0 = *(const short8v*)(Wk + (ct0 + 0) * 1024 + 0 * 512 + lane * 8);
        const short8v bl0 = *(const short8v*)(Wk + (ct0 + 0) * 1024 + 1 * 512 + lane * 8);
        const short8v bh1 = *(const short8v*)(Wk + (ct0 + 1) * 1024 + 0 * 512 + lane * 8);
        const short8v bl1 = *(const short8v*)(Wk + (ct0 + 1) * 1024 + 1 * 512 + lane * 8);

        acc0 = __builtin_amdgcn_mfma_f32_16x16x32_bf16(a_hi, bh0, acc0, 0, 0, 0);
        acc0 = __builtin_amdgcn_mfma_f32_16x16x32_bf16(a_hi, bl0, acc0, 0, 0, 0);
        acc0 = __builtin_amdgcn_mfma_f32_16x16x32_bf16(a_lo, bh0, acc0, 0, 0, 0);
        acc1 = __builtin_amdgcn_mfma_f32_16x16x32_bf16(a_hi, bh1, acc1, 0, 0, 0);
        acc1 = __builtin_amdgcn_mfma_f32_16x16x32_bf16(a_hi, bl1, acc1, 0, 0, 0);
        acc1 = __builtin_amdgcn_mfma_f32_16x16x32_bf16(a_lo, bh1, acc1, 0, 0, 0);
    }

    if (G == nullptr) {
        // ---- Layer-1 epilogue: relu -> bf16 + fp8 stores ----
        #pragma unroll
        for (int reg = 0; reg < 4; ++reg) {
            int n = n0 + rt * 16 + q * 4 + reg;
            if (n < N_NODES) {
                float v0 = fmaxf(acc0[reg], 0.f);
                float v1 = fmaxf(acc1[reg], 0.f);
                outb[(size_t)n * 64 + col0] = f2bf_rne(v0);
                outb[(size_t)n * 64 + col1] = f2bf_rne(v1);
                outq[(size_t)n * 64 + col0] = enc1(v0);
                outq[(size_t)n * 64 + col1] = enc1(v1);
            }
        }
    } else {
        // ---- Layer-2 epilogue: fused per-graph sum-pool ----
        __syncthreads();                      // all hT reads done
        float* outLds = (float*)hT;           // [32][66]
        #pragma unroll
        for (int reg = 0; reg < 4; ++reg) {
            int lr = rt * 16 + q * 4 + reg;
            outLds[lr * 66 + col0] = fmaxf(acc0[reg], 0.f);
            outLds[lr * 66 + col1] = fmaxf(acc1[reg], 0.f);
        }
        if (tid < 32) batch_lds[tid] = (n0 + tid < N_NODES) ? batch[n0 + tid] : -1;
        __syncthreads();
        if (tid < 64) {
            int prev = -1; float acc = 0.f;
            for (int rr = 0; rr < 32; ++rr) {
                int bg = batch_lds[rr];
                if (bg < 0) break;
                if (bg != prev) {
                    if (prev >= 0) unsafeAtomicAdd(&G[prev * 64 + tid], acc);
                    acc = 0.f; prev = bg;
                }
                acc += outLds[rr * 66 + tid];
            }
            if (prev >= 0) unsafeAtomicAdd(&G[prev * 64 + tid], acc);
        }
    }
}

// ---------------------------------------------------------------------------
// Final MLP + softmax: one 64-thread block per graph.
// ---------------------------------------------------------------------------
__global__ __launch_bounds__(64) void mlp_kernel(
    const float* __restrict__ G,      // [256][64]
    const float* __restrict__ Wd1,    // [64][64]
    const float* __restrict__ bd1,    // [64]
    const float* __restrict__ Wd2,    // [64][10]
    const float* __restrict__ bd2,    // [10]
    float* __restrict__ out)          // [256][10]
{
    __shared__ float grow[64];
    __shared__ float h1[64];
    __shared__ float logits[NUM_CLASS];

    const int gI = blockIdx.x;
    const int d = threadIdx.x;

    grow[d] = G[gI * 64 + d];
    __syncthreads();

    float a = bd1[d];
    #pragma unroll 8
    for (int k = 0; k < 64; ++k) a += grow[k] * Wd1[k * 64 + d];
    h1[d] = fmaxf(a, 0.f);
    __syncthreads();

    if (d < NUM_CLASS) {
        float s = bd2[d];
        #pragma unroll 8
        for (int k = 0; k < 64; ++k) s += h1[k] * Wd2[k * 10 + d];
        logits[d] = s;
    }
    __syncthreads();

    if (d < NUM_CLASS) {
        float m = logits[0];
        #pragma unroll
        for (int i = 1; i < NUM_CLASS; ++i) m = fmaxf(m, logits[i]);
        float s = 0.f;
        #pragma unroll
        for (int i = 0; i < NUM_CLASS; ++i) s += expf(logits[i] - m);
        out[gI * NUM_CLASS + d] = expf(logits[d] - m) / s;
    }
}

extern "C" void kernel_launch(void* const* d_in, const int* in_sizes, int n_in,
                              void* d_out, int out_size, void* d_ws, size_t ws_size,
                              hipStream_t stream) {
    const float* x0   = (const float*)d_in[0];
    const int*   edge = (const int*)d_in[1];
    const int*   batch= (const int*)d_in[2];
    const float* W1   = (const float*)d_in[3];
    const float* b1   = (const float*)d_in[4];
    const float* W2   = (const float*)d_in[5];
    const float* b2   = (const float*)d_in[6];
    const float* Wd1  = (const float*)d_in[7];
    const float* bd1  = (const float*)d_in[8];
    const float* Wd2  = (const float*)d_in[9];
    const float* bd2  = (const float*)d_in[10];
    float* out = (float*)d_out;

    const int* src = edge;             // edge_index[0]
    const int* dst = edge + N_EDGES;   // edge_index[1]

    char* ws = (char*)d_ws;
    int*   deg = (int*)ws;                     ws += N_NODES * 4;                  // 200 KB
    unsigned short* csr = (unsigned short*)ws; ws += (size_t)N_NODES * CAP * 2;    // 6.4 MB
    int*   bcount = (int*)ws;                  ws += NB * 4;
    unsigned short* WB = (unsigned short*)ws;  ws += 32768 * 2;                    // 64 KB
    float* G = (float*)ws;                     ws += NUM_GRAPHS * DIM * 4;         // 64 KB
    unsigned* x0q = (unsigned*)ws;             ws += (size_t)N_NODES * 16 * 4;     // 3.2 MB
    unsigned short* Bb = (unsigned short*)ws;  ws += (size_t)N_NODES * DIM * 2;    // 6.4 MB
    unsigned char* Bq = (unsigned char*)ws;    ws += (size_t)N_NODES * DIM;        // 3.2 MB
    unsigned int* bdata = (unsigned int*)ws;   ws += (size_t)NB * BCAP * 4;        // 6.4 MB

    const int bucketBlocks = (I4_TOTAL + I4_PER_BLOCK - 1) / I4_PER_BLOCK;  // 153
    const int nodeBlocks = (N_NODES + 31) / 32;                              // 1563

    // prep: fp8(x0) + packed W + zero(bcount, G)
    prep_kernel<<<3254, 256, 0, stream>>>(
        (const float4*)x0, W1, W2, x0q, WB, bcount, G);

    // Bucketed CSR build (by dst) — reused by both layers
    bucket_kernel<<<bucketBlocks, 512, 0, stream>>>(
        (const int4*)src, (const int4*)dst, bcount, bdata);
    csr_build_kernel<<<NB, 256, 0, stream>>>(bcount, bdata, deg, csr);

    // Layer 1: self f32 x0, gather fp8 x0 -> bf16 Bb + fp8 Bq
    sage_layer_kernel<<<nodeBlocks, 256, 0, stream>>>(
        (const float4*)x0, nullptr, x0q, deg, csr, WB, b1, Bb, Bq, nullptr, nullptr);
    // Layer 2: self bf16 Bb, gather fp8 Bq -> fused per-graph sum-pool into G
    sage_layer_kernel<<<nodeBlocks, 256, 0, stream>>>(
        nullptr, (const ushort4*)Bb, (const unsigned*)Bq, deg, csr, WB + 16384, b2,
        nullptr, nullptr, G, batch);

    // Final MLP + softmax
    mlp_kernel<<<NUM_GRAPHS, 64, 0, stream>>>(G, Wd1, bd1, Wd2, bd2, out);
}

// Round 15
// 94.461 us; speedup vs baseline: 1.0417x; 1.0417x over previous
//
#include <hip/hip_runtime.h>

#define N_NODES 50000
#define N_EDGES 1250000
#define DIM 64
#define NUM_CLASS 10
#define NUM_GRAPHS 256
#define CAP 64        // padded CSR row capacity (deg mean 25, sd 5; max deg << 64)
#define BSHIFT 6      // 64 nodes per bucket
#define NB ((N_NODES + 63) / 64)          // 782 buckets
#define BCAP 2048     // entries per bucket (mean ~1600, sd ~40; +11 sigma)
#define I4_TOTAL (N_EDGES / 4)            // 312500, exact
#define I4_PER_BLOCK 4096                 // 16384 edges/block -> ~21-entry chunks/bucket

typedef __attribute__((ext_vector_type(8))) short short8v;   // 8 bf16 = 4 VGPR
typedef __attribute__((ext_vector_type(4))) float float4v;   // MFMA C/D
typedef __attribute__((ext_vector_type(2))) float float2v;

#if defined(__has_builtin)
#if __has_builtin(__builtin_amdgcn_cvt_pk_f32_fp8) && __has_builtin(__builtin_amdgcn_cvt_pk_fp8_f32)
#define HW_FP8 1
#endif
#endif

__device__ inline unsigned short f2bf_rne(float f) {
    unsigned b = __float_as_uint(f);
    return (unsigned short)((b + 0x7fff + ((b >> 16) & 1)) >> 16);
}
__device__ inline float bf2f(unsigned short u) {
    return __uint_as_float((unsigned)u << 16);
}

// ---- fp8 e4m3fn software helpers (fallback) -------------------------------
__device__ inline unsigned f2e4m3_sw(float x) {
    float af = fabsf(x);
    unsigned s = (__float_as_uint(x) >> 31) << 7;
    if (af >= 448.f) return s | 0x7E;
    if (af < 0.015625f) {
        int n = (int)rintf(af * 512.f);
        if (n >= 8) return s | 0x08;
        return s | (unsigned)n;
    }
    unsigned u = __float_as_uint(af);
    u += 0x7FFFF + ((u >> 20) & 1);
    int e32 = (int)(u >> 23) - 127;
    if (e32 > 8) return s | 0x7E;
    unsigned m = (u >> 20) & 7;
    return s | ((unsigned)(e32 + 7) << 3) | m;
}
__device__ inline float e4m3f_sw(unsigned b) {
    unsigned e = (b >> 3) & 15;
    unsigned nz = e ? 1u : 0u;
    float mant = (float)((b & 7) + (nz << 3));
    float v = ldexpf(mant, (int)e - 9 - (int)nz);
    return (b & 0x80) ? -v : v;
}

__device__ inline float4 dec4(unsigned q) {
#ifdef HW_FP8
    float2v lo = __builtin_amdgcn_cvt_pk_f32_fp8(q, false);
    float2v hi = __builtin_amdgcn_cvt_pk_f32_fp8(q, true);
    return make_float4(lo.x, lo.y, hi.x, hi.y);
#else
    return make_float4(e4m3f_sw(q & 0xff), e4m3f_sw((q >> 8) & 0xff),
                       e4m3f_sw((q >> 16) & 0xff), e4m3f_sw(q >> 24));
#endif
}
__device__ inline unsigned enc4(float a, float b, float c, float d) {
#ifdef HW_FP8
    int u = __builtin_amdgcn_cvt_pk_fp8_f32(a, b, 0, false);
    u = __builtin_amdgcn_cvt_pk_fp8_f32(c, d, u, true);
    return (unsigned)u;
#else
    return f2e4m3_sw(a) | (f2e4m3_sw(b) << 8) | (f2e4m3_sw(c) << 16) | (f2e4m3_sw(d) << 24);
#endif
}
__device__ inline unsigned char enc1(float a) {
#ifdef HW_FP8
    return (unsigned char)(__builtin_amdgcn_cvt_pk_fp8_f32(a, a, 0, false) & 0xff);
#else
    return (unsigned char)f2e4m3_sw(a);
#endif
}

// ---------------------------------------------------------------------------
// Phase A: bucket edges by dst>>6 (LDS histogram -> chunked dense writes).
// ---------------------------------------------------------------------------
__global__ __launch_bounds__(512) void bucket_kernel(
    const int4* __restrict__ src4, const int4* __restrict__ dst4,
    int* __restrict__ bcount, unsigned int* __restrict__ bdata)
{
    __shared__ int hist[NB];
    __shared__ int base[NB];
    const int tid = threadIdx.x;
    for (int k = tid; k < NB; k += 512) hist[k] = 0;
    __syncthreads();

    const int i4base = blockIdx.x * I4_PER_BLOCK;
    const int i4end = min(i4base + I4_PER_BLOCK, I4_TOTAL);

    for (int idx = i4base + tid; idx < i4end; idx += 512) {
        int4 d = dst4[idx];
        atomicAdd(&hist[d.x >> BSHIFT], 1);
        atomicAdd(&hist[d.y >> BSHIFT], 1);
        atomicAdd(&hist[d.z >> BSHIFT], 1);
        atomicAdd(&hist[d.w >> BSHIFT], 1);
    }
    __syncthreads();

    for (int k = tid; k < NB; k += 512) {
        int c = hist[k];
        base[k] = c ? atomicAdd(&bcount[k], c) : 0;
        hist[k] = 0;   // reuse as local cursor
    }
    __syncthreads();

    for (int idx = i4base + tid; idx < i4end; idx += 512) {
        int4 s = src4[idx];   // L2-hit re-read
        int4 d = dst4[idx];
        int k, p;
        k = d.x >> BSHIFT; p = base[k] + atomicAdd(&hist[k], 1);
        if (p < BCAP) bdata[(size_t)k * BCAP + p] = ((unsigned)(d.x & 63) << 16) | (unsigned)s.x;
        k = d.y >> BSHIFT; p = base[k] + atomicAdd(&hist[k], 1);
        if (p < BCAP) bdata[(size_t)k * BCAP + p] = ((unsigned)(d.y & 63) << 16) | (unsigned)s.y;
        k = d.z >> BSHIFT; p = base[k] + atomicAdd(&hist[k], 1);
        if (p < BCAP) bdata[(size_t)k * BCAP + p] = ((unsigned)(d.z & 63) << 16) | (unsigned)s.z;
        k = d.w >> BSHIFT; p = base[k] + atomicAdd(&hist[k], 1);
        if (p < BCAP) bdata[(size_t)k * BCAP + p] = ((unsigned)(d.w & 63) << 16) | (unsigned)s.w;
    }
}

// ---------------------------------------------------------------------------
// Phase B: one block per bucket. Build 64 padded CSR rows in LDS, stream out.
// ---------------------------------------------------------------------------
__global__ __launch_bounds__(256) void csr_build_kernel(
    const int* __restrict__ bcount, const unsigned int* __restrict__ bdata,
    int* __restrict__ deg, unsigned short* __restrict__ csr)
{
    __shared__ unsigned short lcsr[64 * CAP];   // 8 KB
    __shared__ int ldeg[64];
    const int tid = threadIdx.x;
    const int bk = blockIdx.x;
    if (tid < 64) ldeg[tid] = 0;
    __syncthreads();

    const int cnt = min(bcount[bk], BCAP);
    for (int i = tid; i < cnt; i += 256) {
        unsigned int e = bdata[(size_t)bk * BCAP + i];
        int d = (int)(e >> 16);
        int p = atomicAdd(&ldeg[d], 1);
        if (p < CAP) lcsr[d * CAP + p] = (unsigned short)(e & 0xffff);
    }
    __syncthreads();

    const int node0 = bk << BSHIFT;
    const int nlocal = min(64, N_NODES - node0);
    uint4* csr16 = (uint4*)(csr + (size_t)node0 * CAP);
    const uint4* l16 = (const uint4*)lcsr;
    for (int i = tid; i < nlocal * 8; i += 256) csr16[i] = l16[i];
    if (tid < nlocal) deg[node0 + tid] = ldeg[tid];
}

// ---------------------------------------------------------------------------
// prep: [0,3125) x0->fp8; [3125,3253) pack W; block 3253 zero bcount + G.
// ---------------------------------------------------------------------------
__global__ __launch_bounds__(256) void prep_kernel(
    const float4* __restrict__ x04, const float* __restrict__ W1,
    const float* __restrict__ W2, unsigned* __restrict__ x0q,
    unsigned short* __restrict__ WB, int* __restrict__ bcount,
    float* __restrict__ G)
{
    const int bid = blockIdx.x;
    const int tid = threadIdx.x;
    if (bid < 3125) {
        int t = bid * 256 + tid;            // < 800000
        float4 v = x04[t];
        x0q[t] = enc4(v.x, v.y, v.z, v.w);
    } else if (bid < 3253) {
        int t = (bid - 3125) * 256 + tid;   // 0..32767
        int layer = t >> 14;
        int r = t & 16383;
        int i    = r & 7;
        int lane = (r >> 3) & 63;
        int h    = (r >> 9) & 1;
        int ct   = (r >> 10) & 3;
        int kt   = (r >> 12) & 3;
        int k   = kt * 32 + (lane >> 4) * 8 + i;
        int col = ct * 16 + (lane & 15);
        const float* W = layer ? W2 : W1;
        float x = W[k * 64 + col];
        unsigned bits = __float_as_uint(x);
        unsigned short u;
        if (h == 0) {
            u = (unsigned short)(bits >> 16);
        } else {
            float y = x - __uint_as_float(bits & 0xffff0000u);
            u = (unsigned short)(__float_as_uint(y) >> 16);
        }
        WB[t] = u;
    } else {
        for (int k = tid; k < NB; k += 256) bcount[k] = 0;
        for (int k = tid; k < NUM_GRAPHS * DIM; k += 256) G[k] = 0.f;
    }
}

// ---------------------------------------------------------------------------
// Fused SAGE layer. Gather from fp8 copy (64 B/row, L2-resident), HW cvt
// decode, f32 accumulate into hT[128][33]; self from f32 (layer 1) or bf16
// (layer 2). MFMA GEMM (16x16x32 bf16, 3-term hi/lo). Epilogue:
//   layer 1: relu -> bf16 (self for L2) + fp8 (gather for L2)
//   layer 2: relu -> LDS rows -> segmented per-graph sum (batch sorted)
//            -> ~1.2 unsafeAtomicAdd per (block,col) into G[256][64].
// D layout (m89-verified): col=lane&15, row=(lane>>4)*4+reg.
// ---------------------------------------------------------------------------
__global__ __launch_bounds__(256) void sage_layer_kernel(
    const float4* __restrict__ xs4,          // f32 self or null
    const ushort4* __restrict__ xsb,         // bf16 self or null
    const unsigned* __restrict__ xq,         // fp8 gather features [N][16]
    const int* __restrict__ deg,
    const unsigned short* __restrict__ csr,
    const unsigned short* __restrict__ WB,   // packed B-frags (this layer)
    const float* __restrict__ b,             // [64]
    unsigned short* __restrict__ outb,       // bf16 out or null
    unsigned char* __restrict__ outq,        // fp8 out or null
    float* __restrict__ G,                   // pooled sums or null
    const int* __restrict__ batch)
{
    __shared__ float hT[128][33];            // phase2 aliases as out[32][66]
    __shared__ int batch_lds[32];

    const int tid = threadIdx.x;
    const int g = tid >> 4;     // gather group 0..15
    const int c = tid & 15;     // column quad 0..15 (elements 4c..4c+3)
    const int n0 = blockIdx.x * 32;

    // ---- Phase 1: gather-aggregate (fp8 rows), 2 nodes per group ----
    #pragma unroll
    for (int p = 0; p < 2; ++p) {
        const int nl = g + p * 16;      // local node 0..31
        const int n = n0 + nl;
        float4 xv = make_float4(0.f, 0.f, 0.f, 0.f);
        float4 aggv = make_float4(0.f, 0.f, 0.f, 0.f);
        if (n < N_NODES) {
            if (xs4) {
                xv = xs4[(size_t)n * 16 + c];
            } else {
                ushort4 u = xsb[(size_t)n * 16 + c];
                xv = make_float4(bf2f(u.x), bf2f(u.y), bf2f(u.z), bf2f(u.w));
            }
            const int dcount = min(deg[n], CAP);
            const unsigned short* row = csr + (size_t)n * CAP;
            int j = 0;
            for (; j + 8 <= dcount; j += 8) {
                ushort4 sa = *(const ushort4*)(row + j);
                ushort4 sb = *(const ushort4*)(row + j + 4);
                unsigned q0 = xq[(size_t)sa.x * 16 + c];
                unsigned q1 = xq[(size_t)sa.y * 16 + c];
                unsigned q2 = xq[(size_t)sa.z * 16 + c];
                unsigned q3 = xq[(size_t)sa.w * 16 + c];
                unsigned q4 = xq[(size_t)sb.x * 16 + c];
                unsigned q5 = xq[(size_t)sb.y * 16 + c];
                unsigned q6 = xq[(size_t)sb.z * 16 + c];
                unsigned q7 = xq[(size_t)sb.w * 16 + c];
                float4 f0 = dec4(q0), f1 = dec4(q1), f2 = dec4(q2), f3 = dec4(q3);
                float4 f4 = dec4(q4), f5 = dec4(q5), f6 = dec4(q6), f7 = dec4(q7);
                aggv.x += (f0.x + f1.x) + (f2.x + f3.x) + (f4.x + f5.x) + (f6.x + f7.x);
                aggv.y += (f0.y + f1.y) + (f2.y + f3.y) + (f4.y + f5.y) + (f6.y + f7.y);
                aggv.z += (f0.z + f1.z) + (f2.z + f3.z) + (f4.z + f5.z) + (f6.z + f7.z);
                aggv.w += (f0.w + f1.w) + (f2.w + f3.w) + (f4.w + f5.w) + (f6.w + f7.w);
            }
            for (; j < dcount; ++j) {
                int s = row[j];
                float4 f = dec4(xq[(size_t)s * 16 + c]);
                aggv.x += f.x; aggv.y += f.y; aggv.z += f.z; aggv.w += f.w;
            }
        }
        hT[4 * c + 0][nl] = xv.x;
        hT[4 * c + 1][nl] = xv.y;
        hT[4 * c + 2][nl] = xv.z;
        hT[4 * c + 3][nl] = xv.w;
        hT[64 + 4 * c + 0][nl] = aggv.x;
        hT[64 + 4 * c + 1][nl] = aggv.y;
        hT[64 + 4 * c + 2][nl] = aggv.z;
        hT[64 + 4 * c + 3][nl] = aggv.w;
    }
    __syncthreads();

    // ---- Phase 2: MFMA GEMM ----
    const int lane = tid & 63;
    const int wid  = tid >> 6;      // 0..3
    const int rt   = wid >> 1;      // row-tile 0..1
    const int ct0  = (wid & 1) * 2; // col-tiles ct0, ct0+1
    const int r  = lane & 15;
    const int q  = lane >> 4;

    const int col0 = (ct0 + 0) * 16 + r;
    const int col1 = (ct0 + 1) * 16 + r;
    const float bv0 = b[col0];
    const float bv1 = b[col1];
    float4v acc0 = {bv0, bv0, bv0, bv0};
    float4v acc1 = {bv1, bv1, bv1, bv1};

    #pragma unroll
    for (int kt = 0; kt < 4; ++kt) {
        short8v a_hi, a_lo;
        #pragma unroll
        for (int i = 0; i < 8; ++i) {
            float av = hT[kt * 32 + q * 8 + i][rt * 16 + r];
            unsigned bits = __float_as_uint(av);
            a_hi[i] = (short)(bits >> 16);
            float y = av - __uint_as_float(bits & 0xffff0000u);
            a_lo[i] = (short)(__float_as_uint(y) >> 16);
        }
        const unsigned short* Wk = WB + kt * 4096;
        const short8v bh0 = *(const short8v*)(Wk + (ct0 + 0) * 1024 + 0 * 512 + lane * 8);
        const short8v bl0 = *(const short8v*)(Wk + (ct0 + 0) * 1024 + 1 * 512 + lane * 8);
        const short8v bh1 = *(const short8v*)(Wk + (ct0 + 1) * 1024 + 0 * 512 + lane * 8);
        const short8v bl1 = *(const short8v*)(Wk + (ct0 + 1) * 1024 + 1 * 512 + lane * 8);

        acc0 = __builtin_amdgcn_mfma_f32_16x16x32_bf16(a_hi, bh0, acc0, 0, 0, 0);
        acc0 = __builtin_amdgcn_mfma_f32_16x16x32_bf16(a_hi, bl0, acc0, 0, 0, 0);
        acc0 = __builtin_amdgcn_mfma_f32_16x16x32_bf16(a_lo, bh0, acc0, 0, 0, 0);
        acc1 = __builtin_amdgcn_mfma_f32_16x16x32_bf16(a_hi, bh1, acc1, 0, 0, 0);
        acc1 = __builtin_amdgcn_mfma_f32_16x16x32_bf16(a_hi, bl1, acc1, 0, 0, 0);
        acc1 = __builtin_amdgcn_mfma_f32_16x16x32_bf16(a_lo, bh1, acc1, 0, 0, 0);
    }

    if (G == nullptr) {
        // ---- Layer-1 epilogue: relu -> bf16 + fp8 stores ----
        #pragma unroll
        for (int reg = 0; reg < 4; ++reg) {
            int n = n0 + rt * 16 + q * 4 + reg;
            if (n < N_NODES) {
                float v0 = fmaxf(acc0[reg], 0.f);
                float v1 = fmaxf(acc1[reg], 0.f);
                outb[(size_t)n * 64 + col0] = f2bf_rne(v0);
                outb[(size_t)n * 64 + col1] = f2bf_rne(v1);
                outq[(size_t)n * 64 + col0] = enc1(v0);
                outq[(size_t)n * 64 + col1] = enc1(v1);
            }
        }
    } else {
        // ---- Layer-2 epilogue: fused per-graph sum-pool ----
        __syncthreads();                      // all hT reads done
        float* outLds = (float*)hT;           // [32][66]
        #pragma unroll
        for (int reg = 0; reg < 4; ++reg) {
            int lr = rt * 16 + q * 4 + reg;
            outLds[lr * 66 + col0] = fmaxf(acc0[reg], 0.f);
            outLds[lr * 66 + col1] = fmaxf(acc1[reg], 0.f);
        }
        if (tid < 32) batch_lds[tid] = (n0 + tid < N_NODES) ? batch[n0 + tid] : -1;
        __syncthreads();
        if (tid < 64) {
            int prev = -1; float acc = 0.f;
            for (int rr = 0; rr < 32; ++rr) {
                int bg = batch_lds[rr];
                if (bg < 0) break;
                if (bg != prev) {
                    if (prev >= 0) unsafeAtomicAdd(&G[prev * 64 + tid], acc);
                    acc = 0.f; prev = bg;
                }
                acc += outLds[rr * 66 + tid];
            }
            if (prev >= 0) unsafeAtomicAdd(&G[prev * 64 + tid], acc);
        }
    }
}

// ---------------------------------------------------------------------------
// Final MLP + softmax: one 64-thread block per graph.
// ---------------------------------------------------------------------------
__global__ __launch_bounds__(64) void mlp_kernel(
    const float* __restrict__ G,      // [256][64]
    const float* __restrict__ Wd1,    // [64][64]
    const float* __restrict__ bd1,    // [64]
    const float* __restrict__ Wd2,    // [64][10]
    const float* __restrict__ bd2,    // [10]
    float* __restrict__ out)          // [256][10]
{
    __shared__ float grow[64];
    __shared__ float h1[64];
    __shared__ float logits[NUM_CLASS];

    const int gI = blockIdx.x;
    const int d = threadIdx.x;

    grow[d] = G[gI * 64 + d];
    __syncthreads();

    float a = bd1[d];
    #pragma unroll 8
    for (int k = 0; k < 64; ++k) a += grow[k] * Wd1[k * 64 + d];
    h1[d] = fmaxf(a, 0.f);
    __syncthreads();

    if (d < NUM_CLASS) {
        float s = bd2[d];
        #pragma unroll 8
        for (int k = 0; k < 64; ++k) s += h1[k] * Wd2[k * 10 + d];
        logits[d] = s;
    }
    __syncthreads();

    if (d < NUM_CLASS) {
        float m = logits[0];
        #pragma unroll
        for (int i = 1; i < NUM_CLASS; ++i) m = fmaxf(m, logits[i]);
        float s = 0.f;
        #pragma unroll
        for (int i = 0; i < NUM_CLASS; ++i) s += expf(logits[i] - m);
        out[gI * NUM_CLASS + d] = expf(logits[d] - m) / s;
    }
}

extern "C" void kernel_launch(void* const* d_in, const int* in_sizes, int n_in,
                              void* d_out, int out_size, void* d_ws, size_t ws_size,
                              hipStream_t stream) {
    const float* x0   = (const float*)d_in[0];
    const int*   edge = (const int*)d_in[1];
    const int*   batch= (const int*)d_in[2];
    const float* W1   = (const float*)d_in[3];
    const float* b1   = (const float*)d_in[4];
    const float* W2   = (const float*)d_in[5];
    const float* b2   = (const float*)d_in[6];
    const float* Wd1  = (const float*)d_in[7];
    const float* bd1  = (const float*)d_in[8];
    const float* Wd2  = (const float*)d_in[9];
    const float* bd2  = (const float*)d_in[10];
    float* out = (float*)d_out;

    const int* src = edge;             // edge_index[0]
    const int* dst = edge + N_EDGES;   // edge_index[1]

    char* ws = (char*)d_ws;
    int*   deg = (int*)ws;                     ws += N_NODES * 4;                  // 200 KB
    unsigned short* csr = (unsigned short*)ws; ws += (size_t)N_NODES * CAP * 2;    // 6.4 MB
    int*   bcount = (int*)ws;                  ws += NB * 4;
    unsigned short* WB = (unsigned short*)ws;  ws += 32768 * 2;                    // 64 KB
    float* G = (float*)ws;                     ws += NUM_GRAPHS * DIM * 4;         // 64 KB
    unsigned* x0q = (unsigned*)ws;             ws += (size_t)N_NODES * 16 * 4;     // 3.2 MB
    unsigned short* Bb = (unsigned short*)ws;  ws += (size_t)N_NODES * DIM * 2;    // 6.4 MB
    unsigned char* Bq = (unsigned char*)ws;    ws += (size_t)N_NODES * DIM;        // 3.2 MB
    unsigned int* bdata = (unsigned int*)ws;   ws += (size_t)NB * BCAP * 4;        // 6.4 MB

    const int bucketBlocks = (I4_TOTAL + I4_PER_BLOCK - 1) / I4_PER_BLOCK;  // 77
    const int nodeBlocks = (N_NODES + 31) / 32;                              // 1563

    // prep: fp8(x0) + packed W + zero(bcount, G)
    prep_kernel<<<3254, 256, 0, stream>>>(
        (const float4*)x0, W1, W2, x0q, WB, bcount, G);

    // Bucketed CSR build (by dst) — reused by both layers
    bucket_kernel<<<bucketBlocks, 512, 0, stream>>>(
        (const int4*)src, (const int4*)dst, bcount, bdata);
    csr_build_kernel<<<NB, 256, 0, stream>>>(bcount, bdata, deg, csr);

    // Layer 1: self f32 x0, gather fp8 x0 -> bf16 Bb + fp8 Bq
    sage_layer_kernel<<<nodeBlocks, 256, 0, stream>>>(
        (const float4*)x0, nullptr, x0q, deg, csr, WB, b1, Bb, Bq, nullptr, nullptr);
    // Layer 2: self bf16 Bb, gather fp8 Bq -> fused per-graph sum-pool into G
    sage_layer_kernel<<<nodeBlocks, 256, 0, stream>>>(
        nullptr, (const ushort4*)Bb, (const unsigned*)Bq, deg, csr, WB + 16384, b2,
        nullptr, nullptr, G, batch);

    // Final MLP + softmax
    mlp_kernel<<<NUM_GRAPHS, 64, 0, stream>>>(G, Wd1, bd1, Wd2, bd2, out);
}